// Round 1
// baseline (107.682 us; speedup 1.0000x reference)
//
#include <hip/hip_runtime.h>

#define NH 16
#define HD 64
#define LSEQ 2048
#define BQ 128
#define BK 64
#define NQT (LSEQ / BQ)          // 16
#define RS (NH * HD)             // 1024 floats per token row
#define NTILE 4                  // kt = 2qt-1 .. 2qt+2; dropped tiles have weight <= e^-56

typedef __bf16 bf16x8 __attribute__((ext_vector_type(8)));
typedef float f32x4 __attribute__((ext_vector_type(4)));

// exp(-8): folds the fixed softmax shift into the mask multiplier; cancels in O/l.
#define EXP_NEG8 0.00033546262790251185f

__global__ __launch_bounds__(512, 4)
void attn_kernel(const float* __restrict__ Q,
                 const float* __restrict__ K,
                 const float* __restrict__ V,
                 const int* __restrict__ Mk,
                 float* __restrict__ Out)
{
    // K/V double-buffered: [K0|K1|V0|V1], each 64x72 bf16 (9216 B) = 36864 B.
    // Reused after the loop as float oscr[128][68] (34816 B) for the coalesced epilogue.
    __shared__ alignas(16) char smem_raw[4 * 64 * 72 * 2];
    __shared__ alignas(16) __bf16 sP[8][16][72];
    __bf16* kvb = (__bf16*)smem_raw;

    const int tid  = threadIdx.x;
    const int wave = tid >> 6;
    const int lane = tid & 63;
    const int ln   = lane & 15;
    const int quad = lane >> 4;

    // XCD-bijective swizzle: dispatch id round-robins XCDs (bid&7); give each XCD a
    // contiguous 64-work chunk so the qt/qt+1 pair sharing 3 of 4 K/V tiles lands on
    // the SAME XCD L2 (the 2x re-read hits L2 instead of L3).
    const unsigned bid = blockIdx.x;
    const unsigned w   = (bid & 7u) * 64u + (bid >> 3);
    const int qt = w & (NQT - 1);
    const int bh = w >> 4;
    const int b  = bh >> 4;
    const int h  = bh & 15;

    const int q0   = qt * BQ;
    const int qrow = q0 + wave * 16;

    const size_t bh_off = ((size_t)b * LSEQ) * RS + (size_t)h * HD;
    const float* gQ = Q + bh_off;
    const float* gK = K + bh_off;
    const float* gV = V + bh_off;
    const int*   gM = Mk + (size_t)b * LSEQ;
    float*       gO = Out + bh_off;

    // staging map: idx = tid + i*512 -> (row 0..63, 16B chunk 0..15)
    int srow[2], sc4[2];
#pragma unroll
    for (int i = 0; i < 2; ++i) { int idx = tid + i * 512; srow[i] = idx >> 4; sc4[i] = idx & 15; }

    // ---- Q fragments (A-operand), pre-scaled by 1/sqrt(D)
    bf16x8 qfrag[2];
#pragma unroll
    for (int c = 0; c < 2; ++c) {
        const float* src = gQ + (size_t)(qrow + ln) * RS + c * 32 + quad * 8;
        float4 f0 = *(const float4*)(src);
        float4 f1 = *(const float4*)(src + 4);
        bf16x8 t;
        t[0] = (__bf16)(f0.x * 0.125f); t[1] = (__bf16)(f0.y * 0.125f);
        t[2] = (__bf16)(f0.z * 0.125f); t[3] = (__bf16)(f0.w * 0.125f);
        t[4] = (__bf16)(f1.x * 0.125f); t[5] = (__bf16)(f1.y * 0.125f);
        t[6] = (__bf16)(f1.z * 0.125f); t[7] = (__bf16)(f1.w * 0.125f);
        qfrag[c] = t;
    }

    f32x4 o_acc[4];
#pragma unroll
    for (int i = 0; i < 4; ++i) o_acc[i] = f32x4{0.f, 0.f, 0.f, 0.f};
    float l_part[4] = {0.f, 0.f, 0.f, 0.f};

    int k0s[NTILE];
#pragma unroll
    for (int j = 0; j < NTILE; ++j) k0s[j] = ((2 * qt + 31 + j) & 31) * BK;

    float4 kreg[2], vreg[2];
    int mr[4];
#pragma unroll
    for (int i = 0; i < 2; ++i) {
        kreg[i] = *(const float4*)(gK + (size_t)(k0s[0] + srow[i]) * RS + sc4[i] * 4);
        vreg[i] = *(const float4*)(gV + (size_t)(k0s[0] + srow[i]) * RS + sc4[i] * 4);
    }
#pragma unroll
    for (int t = 0; t < 4; ++t) mr[t] = gM[k0s[0] + t * 16 + ln];

#pragma unroll
    for (int j = 0; j < NTILE; ++j) {
        const int bb = j & 1;
        __bf16* sKb = kvb + bb * 4608;          // [64][72]
        __bf16* sVb = kvb + 9216 + bb * 4608;   // [64][72], transposed V: [d][k], k XOR-swizzled

        // ---- store prefetched tile into this iter's buffer ----
#pragma unroll
        for (int i = 0; i < 2; ++i) {
            float4 f = kreg[i];
            __bf16* dst = sKb + srow[i] * 72 + sc4[i] * 4;
            dst[0] = (__bf16)f.x; dst[1] = (__bf16)f.y;
            dst[2] = (__bf16)f.z; dst[3] = (__bf16)f.w;
            float4 g = vreg[i];
            // V^T store: row d = sc4*4+c, col k = srow ^ ((d>>2)&7)<<3.
            // d>>2 == sc4 for all 4 c's, so the XOR key is per-thread constant.
            // Kills the 8-way bank conflict (16 sc4-lanes spread over 8 banks, 2-way = free).
            const int vk = srow[i] ^ ((sc4[i] & 7) << 3);
            sVb[(sc4[i] * 4 + 0) * 72 + vk] = (__bf16)g.x;
            sVb[(sc4[i] * 4 + 1) * 72 + vk] = (__bf16)g.y;
            sVb[(sc4[i] * 4 + 2) * 72 + vk] = (__bf16)g.z;
            sVb[(sc4[i] * 4 + 3) * 72 + vk] = (__bf16)g.w;
        }
        float mm[4];
#pragma unroll
        for (int t = 0; t < 4; ++t) mm[t] = mr[t] ? EXP_NEG8 : 0.f;

        // ---- prefetch next tile ----
        if (j + 1 < NTILE) {
            const int k0n = k0s[j + 1];
#pragma unroll
            for (int i = 0; i < 2; ++i) {
                kreg[i] = *(const float4*)(gK + (size_t)(k0n + srow[i]) * RS + sc4[i] * 4);
                vreg[i] = *(const float4*)(gV + (size_t)(k0n + srow[i]) * RS + sc4[i] * 4);
            }
#pragma unroll
            for (int t = 0; t < 4; ++t) mr[t] = gM[k0n + t * 16 + ln];
        }
        __syncthreads();   // single barrier per tile (double-buffered K/V)

        // ---- S = Q K^T ----
        const int k0 = k0s[j];
        f32x4 s[4];
#pragma unroll
        for (int t = 0; t < 4; ++t) {
            f32x4 acc = f32x4{0.f, 0.f, 0.f, 0.f};
#pragma unroll
            for (int ch = 0; ch < 2; ++ch) {
                bf16x8 bk = *(const bf16x8*)(sKb + (t * 16 + ln) * 72 + ch * 32 + quad * 8);
                acc = __builtin_amdgcn_mfma_f32_16x16x32_bf16(qfrag[ch], bk, acc, 0, 0, 0);
            }
            s[t] = acc;
        }

        // ---- fixed-shift softmax: p = exp(s - d) * (mask ? e^-8 : 0); no reductions ----
        const int qg0 = qrow + quad * 4;
#pragma unroll
        for (int t = 0; t < 4; ++t) {
            const int kg = k0 + t * 16 + ln;
#pragma unroll
            for (int r = 0; r < 4; ++r) {
                int dd = qg0 + r - kg; dd = dd < 0 ? -dd : dd;
                int d2 = LSEQ - dd; dd = d2 < dd ? d2 : dd;
                float p = __expf(s[t][r] - (float)dd) * mm[t];
                l_part[r] += p;
                // sP XOR-swizzle: col ^= (row>>2)<<3; row = quad*4+r so key = quad.
                // Spreads the 4 quad groups over disjoint bank quartets (conflict-free writes).
                sP[wave][quad * 4 + r][(t * 16 + ln) ^ (quad << 3)] = (__bf16)p;
            }
        }

        // ---- O += P V ----
#pragma unroll
        for (int ch = 0; ch < 2; ++ch) {
            // read row = ln -> key = ln>>2; XOR by multiple of 8 keeps the bf16x8 contiguous+16B aligned
            bf16x8 pa = *(const bf16x8*)&sP[wave][ln][(ch * 32 + quad * 8) ^ ((ln >> 2) << 3)];
#pragma unroll
            for (int nt = 0; nt < 4; ++nt) {
                const int vr = nt * 16 + ln;
                const int vc = (ch * 32 + quad * 8) ^ (((vr >> 2) & 7) << 3);
                bf16x8 bv = *(const bf16x8*)(sVb + vr * 72 + vc);
                o_acc[nt] = __builtin_amdgcn_mfma_f32_16x16x32_bf16(pa, bv, o_acc[nt], 0, 0, 0);
            }
        }
        // no trailing barrier: next iter writes the other buffer; its barrier orders reuse.
    }

    // ---- epilogue: reduce l (once), divide, coalesced float4 stores via LDS ----
    float inv[4];
#pragma unroll
    for (int r = 0; r < 4; ++r) {
        float l = l_part[r];
#pragma unroll
        for (int off = 1; off < 16; off <<= 1)
            l += __shfl_xor(l, off, 64);
        inv[r] = 1.f / l;
    }

    __syncthreads();   // everyone done reading K/V buffers
    // stride 68 (=17 dwords, 272 B: 16B-aligned rows) instead of 64: row term 4*row mod 32
    // varies with quad, so the 4 quad lanes stop colliding on one bank (4-way -> free).
    float* oscr = (float*)smem_raw;    // [128][68]
#pragma unroll
    for (int r = 0; r < 4; ++r)
#pragma unroll
        for (int nt = 0; nt < 4; ++nt)
            oscr[(wave * 16 + quad * 4 + r) * 68 + nt * 16 + ln] = o_acc[nt][r] * inv[r];
    __syncthreads();

#pragma unroll
    for (int p = 0; p < 4; ++p) {
        int f   = tid + p * 512;
        int row = f >> 4;
        int c4  = f & 15;
        float4 val = *(const float4*)&oscr[row * 68 + c4 * 4];
        *(float4*)(gO + (size_t)(q0 + row) * RS + c4 * 4) = val;
    }
}

extern "C" void kernel_launch(void* const* d_in, const int* in_sizes, int n_in,
                              void* d_out, int out_size, void* d_ws, size_t ws_size,
                              hipStream_t stream) {
    const float* Q  = (const float*)d_in[0];
    const float* K  = (const float*)d_in[1];
    const float* V  = (const float*)d_in[2];
    const int*   Mk = (const int*)d_in[3];
    float*       O  = (float*)d_out;

    dim3 grid(2 * NH * NQT);   // 512 blocks
    dim3 block(512);
    attn_kernel<<<grid, block, 0, stream>>>(Q, K, V, Mk, O);
}

// Round 2
// 103.764 us; speedup vs baseline: 1.0378x; 1.0378x over previous
//
#include <hip/hip_runtime.h>

#define NH 16
#define HD 64
#define LSEQ 2048
#define BQ 128
#define BK 64
#define NQT (LSEQ / BQ)          // 16
#define RS (NH * HD)             // 1024 floats per token row
#define NTILE 4                  // kt = 2qt-1 .. 2qt+2; dropped tiles have weight <= e^-56

typedef __bf16 bf16x8 __attribute__((ext_vector_type(8)));
typedef float f32x4 __attribute__((ext_vector_type(4)));

// exp(-8): folds the fixed softmax shift into the mask multiplier; cancels in O/l.
#define EXP_NEG8 0.00033546262790251185f

__global__ __launch_bounds__(512, 4)
void attn_kernel(const float* __restrict__ Q,
                 const float* __restrict__ K,
                 const float* __restrict__ V,
                 const int* __restrict__ Mk,
                 float* __restrict__ Out)
{
    // K/V double-buffered: [K0|K1|V0|V1], each 64x72 bf16 (9216 B) = 36864 B.
    // No sP buffer: swapped QK^T keeps P lane-local for PV (see pi-permutation below).
    // Reused after the loop as float oscr[128][68] (34816 B) for the coalesced epilogue.
    __shared__ alignas(16) char smem_raw[4 * 64 * 72 * 2];
    __bf16* kvb = (__bf16*)smem_raw;

    const int tid  = threadIdx.x;
    const int wave = tid >> 6;
    const int lane = tid & 63;
    const int ln   = lane & 15;
    const int quad = lane >> 4;

    const int qt = blockIdx.x & (NQT - 1);   // identity mapping (XCD swizzle reverted: L3-fit regime)
    const int bh = blockIdx.x >> 4;
    const int b  = bh >> 4;
    const int h  = bh & 15;

    const int q0   = qt * BQ;
    const int qrow = q0 + wave * 16;

    const size_t bh_off = ((size_t)b * LSEQ) * RS + (size_t)h * HD;
    const float* gQ = Q + bh_off;
    const float* gK = K + bh_off;
    const float* gV = V + bh_off;
    const int*   gM = Mk + (size_t)b * LSEQ;
    float*       gO = Out + bh_off;

    // staging map: idx = tid + i*512 -> (row 0..63, 16B chunk 0..15)
    int srow[2], sc4[2];
#pragma unroll
    for (int i = 0; i < 2; ++i) { int idx = tid + i * 512; srow[i] = idx >> 4; sc4[i] = idx & 15; }

    // V key-permutation: PV A-frag slot s (= ch*32 + quad*8 + e) carries actual key
    // pi(s) = (ch*2 + (e>>2))*16 + quad*4 + (e&3)  -- exactly the key the lane owns after
    // swapped QK^T. Stage V[k] at column slot = pi^-1(k) so B reads need no remap.
    int vslot[2];
#pragma unroll
    for (int i = 0; i < 2; ++i) {
        int k = srow[i];
        vslot[i] = (k & 32) | ((k & 12) << 1) | ((k & 16) >> 2) | (k & 3);
    }

    // ---- Q fragments (B-operand now; same per-lane data as A-layout), pre-scaled by 1/sqrt(D)
    bf16x8 qfrag[2];
#pragma unroll
    for (int c = 0; c < 2; ++c) {
        const float* src = gQ + (size_t)(qrow + ln) * RS + c * 32 + quad * 8;
        float4 f0 = *(const float4*)(src);
        float4 f1 = *(const float4*)(src + 4);
        bf16x8 t;
        t[0] = (__bf16)(f0.x * 0.125f); t[1] = (__bf16)(f0.y * 0.125f);
        t[2] = (__bf16)(f0.z * 0.125f); t[3] = (__bf16)(f0.w * 0.125f);
        t[4] = (__bf16)(f1.x * 0.125f); t[5] = (__bf16)(f1.y * 0.125f);
        t[6] = (__bf16)(f1.z * 0.125f); t[7] = (__bf16)(f1.w * 0.125f);
        qfrag[c] = t;
    }

    f32x4 o_acc[4];
#pragma unroll
    for (int i = 0; i < 4; ++i) o_acc[i] = f32x4{0.f, 0.f, 0.f, 0.f};
    float l_part = 0.f;   // per-lane: softmax denom for q-row (qrow + ln)

    int k0s[NTILE];
#pragma unroll
    for (int j = 0; j < NTILE; ++j) k0s[j] = ((2 * qt + 31 + j) & 31) * BK;

    float4 kreg[2], vreg[2];
#pragma unroll
    for (int i = 0; i < 2; ++i) {
        kreg[i] = *(const float4*)(gK + (size_t)(k0s[0] + srow[i]) * RS + sc4[i] * 4);
        vreg[i] = *(const float4*)(gV + (size_t)(k0s[0] + srow[i]) * RS + sc4[i] * 4);
    }
    // mask as a wave-wide bitset: one load + ballot per wave per tile
    unsigned long long mbits = __ballot(gM[k0s[0] + lane] != 0);

#pragma unroll
    for (int j = 0; j < NTILE; ++j) {
        const int bb = j & 1;
        __bf16* sKb = kvb + bb * 4608;          // [64][72]
        __bf16* sVb = kvb + 9216 + bb * 4608;   // [64][72]: [d][pi^-1(k) ^ kappa(d)]

        // ---- store prefetched tile into this iter's buffer ----
#pragma unroll
        for (int i = 0; i < 2; ++i) {
            float4 f = kreg[i];
            __bf16* dst = sKb + srow[i] * 72 + sc4[i] * 4;
            dst[0] = (__bf16)f.x; dst[1] = (__bf16)f.y;
            dst[2] = (__bf16)f.z; dst[3] = (__bf16)f.w;
            float4 g = vreg[i];
            // kappa(d) = ((d>>2)&7)<<3; d = sc4*4+c so d>>2 == sc4 for all 4 c's.
            const int vk = vslot[i] ^ ((sc4[i] & 7) << 3);
            sVb[(sc4[i] * 4 + 0) * 72 + vk] = (__bf16)g.x;
            sVb[(sc4[i] * 4 + 1) * 72 + vk] = (__bf16)g.y;
            sVb[(sc4[i] * 4 + 2) * 72 + vk] = (__bf16)g.z;
            sVb[(sc4[i] * 4 + 3) * 72 + vk] = (__bf16)g.w;
        }
        const unsigned long long mb = mbits;

        // ---- prefetch next tile ----
        if (j + 1 < NTILE) {
            const int k0n = k0s[j + 1];
#pragma unroll
            for (int i = 0; i < 2; ++i) {
                kreg[i] = *(const float4*)(gK + (size_t)(k0n + srow[i]) * RS + sc4[i] * 4);
                vreg[i] = *(const float4*)(gV + (size_t)(k0n + srow[i]) * RS + sc4[i] * 4);
            }
            mbits = __ballot(gM[k0n + lane] != 0);
        }
        __syncthreads();   // single barrier per tile (double-buffered K/V)

        // ---- S^T = K Q^T : lane (ln,quad) gets S[key = t*16+quad*4+r][q = qrow+ln] ----
        const int k0 = k0s[j];
        f32x4 s[4];
#pragma unroll
        for (int t = 0; t < 4; ++t) {
            f32x4 acc = f32x4{0.f, 0.f, 0.f, 0.f};
#pragma unroll
            for (int ch = 0; ch < 2; ++ch) {
                bf16x8 ak = *(const bf16x8*)(sKb + (t * 16 + ln) * 72 + ch * 32 + quad * 8);
                acc = __builtin_amdgcn_mfma_f32_16x16x32_bf16(ak, qfrag[ch], acc, 0, 0, 0);
            }
            s[t] = acc;
        }

        // ---- fixed-shift softmax: p = exp(s - d) * (mask ? e^-8 : 0); lane-local ----
        const int qg = qrow + ln;
#pragma unroll
        for (int t = 0; t < 4; ++t) {
            const unsigned nib = (unsigned)(mb >> (t * 16 + quad * 4)) & 0xFu;
#pragma unroll
            for (int r = 0; r < 4; ++r) {
                const int kg = k0 + t * 16 + quad * 4 + r;
                int dd = qg - kg; dd = dd < 0 ? -dd : dd;
                int d2 = LSEQ - dd; dd = d2 < dd ? d2 : dd;
                float mmv = ((nib >> r) & 1u) ? EXP_NEG8 : 0.f;
                float p = __expf(s[t][r] - (float)dd) * mmv;
                l_part += p;
                s[t][r] = p;
            }
        }

        // ---- O += P V : P-frag is lane-local (keys pre-permuted into V's columns) ----
#pragma unroll
        for (int ch = 0; ch < 2; ++ch) {
            bf16x8 pa;
#pragma unroll
            for (int e = 0; e < 8; ++e)
                pa[e] = (__bf16)s[ch * 2 + (e >> 2)][e & 3];
#pragma unroll
            for (int nt = 0; nt < 4; ++nt) {
                const int vr = nt * 16 + ln;
                const int vc = (ch * 32 + quad * 8) ^ (((vr >> 2) & 7) << 3);
                bf16x8 bv = *(const bf16x8*)(sVb + vr * 72 + vc);
                o_acc[nt] = __builtin_amdgcn_mfma_f32_16x16x32_bf16(pa, bv, o_acc[nt], 0, 0, 0);
            }
        }
        // no trailing barrier: next iter writes the other buffer; its barrier orders reuse.
    }

    // ---- epilogue: reduce l over quads, redistribute, divide, coalesced stores via LDS ----
    float lf = l_part;
    lf += __shfl_xor(lf, 16, 64);
    lf += __shfl_xor(lf, 32, 64);   // lane (ln,*): full denom for q-row qrow+ln
    float inv[4];
#pragma unroll
    for (int r = 0; r < 4; ++r)
        inv[r] = 1.f / __shfl(lf, quad * 4 + r, 16);   // o_acc rows are qrow + quad*4 + r

    __syncthreads();   // everyone done reading K/V buffers
    // stride 68 (=17 dwords, 272 B rows, 16B-aligned): quad lanes spread across banks.
    float* oscr = (float*)smem_raw;    // [128][68]
#pragma unroll
    for (int r = 0; r < 4; ++r)
#pragma unroll
        for (int nt = 0; nt < 4; ++nt)
            oscr[(wave * 16 + quad * 4 + r) * 68 + nt * 16 + ln] = o_acc[nt][r] * inv[r];
    __syncthreads();

#pragma unroll
    for (int p = 0; p < 4; ++p) {
        int f   = tid + p * 512;
        int row = f >> 4;
        int c4  = f & 15;
        float4 val = *(const float4*)&oscr[row * 68 + c4 * 4];
        *(float4*)(gO + (size_t)(q0 + row) * RS + c4 * 4) = val;
    }
}

extern "C" void kernel_launch(void* const* d_in, const int* in_sizes, int n_in,
                              void* d_out, int out_size, void* d_ws, size_t ws_size,
                              hipStream_t stream) {
    const float* Q  = (const float*)d_in[0];
    const float* K  = (const float*)d_in[1];
    const float* V  = (const float*)d_in[2];
    const int*   Mk = (const int*)d_in[3];
    float*       O  = (float*)d_out;

    dim3 grid(2 * NH * NQT);   // 512 blocks
    dim3 block(512);
    attn_kernel<<<grid, block, 0, stream>>>(Q, K, V, Mk, O);
}

// Round 3
// 100.131 us; speedup vs baseline: 1.0754x; 1.0363x over previous
//
#include <hip/hip_runtime.h>

#define NH 16
#define HD 64
#define LSEQ 2048
#define BQ 256                   // 2 q-tiles merged per block: k-window union is 6 tiles, not 8
#define BK 64
#define NBLKQ (LSEQ / BQ)        // 8
#define RS (NH * HD)             // 1024 floats per token row
#define NTILE 6                  // tiles 4bq-1 .. 4bq+4; per-q-row window identical to the 4-tile/128-row version

typedef __bf16 bf16x8 __attribute__((ext_vector_type(8)));
typedef float f32x4 __attribute__((ext_vector_type(4)));

// exp(-8): folds the fixed softmax shift into the mask multiplier; cancels in O/l.
#define EXP_NEG8 0.00033546262790251185f

__global__ __launch_bounds__(1024, 4)
void attn_kernel(const float* __restrict__ Q,
                 const float* __restrict__ K,
                 const float* __restrict__ V,
                 const int* __restrict__ Mk,
                 float* __restrict__ Out)
{
    // K/V double-buffered: [K0|K1|V0|V1], each 64x72 bf16 (9216 B) = 36864 B.
    // No sP buffer (swapped QK^T keeps P lane-local). Reused after the loop as
    // float oscr[128][68] (34816 B) for the coalesced epilogue (two 128-row passes).
    __shared__ alignas(16) char smem_raw[4 * 64 * 72 * 2];
    __bf16* kvb = (__bf16*)smem_raw;

    const int tid  = threadIdx.x;
    const int wave = tid >> 6;       // 0..15
    const int lane = tid & 63;
    const int ln   = lane & 15;
    const int quad = lane >> 4;
    const int grp  = wave >> 3;      // 0: q-rows [q0,q0+128), active j=0..3; 1: [q0+128,q0+256), j=2..5
    const int w8   = wave & 7;

    const int bq = blockIdx.x & (NBLKQ - 1);
    const int bh = blockIdx.x >> 3;
    const int b  = bh >> 4;
    const int h  = bh & 15;

    const int q0   = bq * BQ;
    const int qrow = q0 + grp * 128 + w8 * 16;

    const size_t bh_off = ((size_t)b * LSEQ) * RS + (size_t)h * HD;
    const float* gQ = Q + bh_off;
    const float* gK = K + bh_off;
    const float* gV = V + bh_off;
    const int*   gM = Mk + (size_t)b * LSEQ;
    float*       gO = Out + bh_off;

    // staging map: tid -> (row 0..63, 16B chunk 0..15); exactly one float4 of K and V per thread
    const int srow = tid >> 4;
    const int sc4  = tid & 15;

    // V key-permutation: PV A-frag slot s (= ch*32 + quad*8 + e) carries actual key
    // pi(s) = (ch*2 + (e>>2))*16 + quad*4 + (e&3). Stage V[k] at column pi^-1(k).
    const int vslot = (srow & 32) | ((srow & 12) << 1) | ((srow & 16) >> 2) | (srow & 3);

    // ---- Q fragments (B-operand), pre-scaled by 1/sqrt(D)
    bf16x8 qfrag[2];
#pragma unroll
    for (int c = 0; c < 2; ++c) {
        const float* src = gQ + (size_t)(qrow + ln) * RS + c * 32 + quad * 8;
        float4 f0 = *(const float4*)(src);
        float4 f1 = *(const float4*)(src + 4);
        bf16x8 t;
        t[0] = (__bf16)(f0.x * 0.125f); t[1] = (__bf16)(f0.y * 0.125f);
        t[2] = (__bf16)(f0.z * 0.125f); t[3] = (__bf16)(f0.w * 0.125f);
        t[4] = (__bf16)(f1.x * 0.125f); t[5] = (__bf16)(f1.y * 0.125f);
        t[6] = (__bf16)(f1.z * 0.125f); t[7] = (__bf16)(f1.w * 0.125f);
        qfrag[c] = t;
    }

    f32x4 o_acc[4];
#pragma unroll
    for (int i = 0; i < 4; ++i) o_acc[i] = f32x4{0.f, 0.f, 0.f, 0.f};
    float l_part = 0.f;   // per-lane: softmax denom for q-row (qrow + ln)

    int k0s[NTILE];
#pragma unroll
    for (int j = 0; j < NTILE; ++j) k0s[j] = ((4 * bq + 31 + j) & 31) * BK;

    float4 kreg, vreg;
    kreg = *(const float4*)(gK + (size_t)(k0s[0] + srow) * RS + sc4 * 4);
    vreg = *(const float4*)(gV + (size_t)(k0s[0] + srow) * RS + sc4 * 4);
    // mask as a wave-wide bitset: one load + ballot per wave per tile
    unsigned long long mbits = __ballot(gM[k0s[0] + lane] != 0);

#pragma unroll
    for (int j = 0; j < NTILE; ++j) {
        const int bb = j & 1;
        __bf16* sKb = kvb + bb * 4608;          // [64][72]
        __bf16* sVb = kvb + 9216 + bb * 4608;   // [64][72]: [d][pi^-1(k) ^ kappa(d)]

        // ---- store prefetched tile into this iter's buffer ----
        {
            float4 f = kreg;
            __bf16* dst = sKb + srow * 72 + sc4 * 4;
            dst[0] = (__bf16)f.x; dst[1] = (__bf16)f.y;
            dst[2] = (__bf16)f.z; dst[3] = (__bf16)f.w;
            float4 g = vreg;
            // kappa(d) = ((d>>2)&7)<<3; d = sc4*4+c so d>>2 == sc4 for all 4 c's.
            const int vk = vslot ^ ((sc4 & 7) << 3);
            sVb[(sc4 * 4 + 0) * 72 + vk] = (__bf16)g.x;
            sVb[(sc4 * 4 + 1) * 72 + vk] = (__bf16)g.y;
            sVb[(sc4 * 4 + 2) * 72 + vk] = (__bf16)g.z;
            sVb[(sc4 * 4 + 3) * 72 + vk] = (__bf16)g.w;
        }
        const unsigned long long mb = mbits;

        // ---- prefetch next tile ----
        if (j + 1 < NTILE) {
            const int k0n = k0s[j + 1];
            kreg = *(const float4*)(gK + (size_t)(k0n + srow) * RS + sc4 * 4);
            vreg = *(const float4*)(gV + (size_t)(k0n + srow) * RS + sc4 * 4);
            mbits = __ballot(gM[k0n + lane] != 0);
        }
        __syncthreads();   // single barrier per tile (double-buffered K/V)

        // group-activity: wave-uniform, compile-time j
        const bool act = grp ? (j >= 2) : (j <= 3);
        if (act) {
            // ---- S^T = K Q^T : lane (ln,quad) gets S[key = t*16+quad*4+r][q = qrow+ln] ----
            const int k0 = k0s[j];
            f32x4 s[4];
#pragma unroll
            for (int t = 0; t < 4; ++t) {
                f32x4 acc = f32x4{0.f, 0.f, 0.f, 0.f};
#pragma unroll
                for (int ch = 0; ch < 2; ++ch) {
                    bf16x8 ak = *(const bf16x8*)(sKb + (t * 16 + ln) * 72 + ch * 32 + quad * 8);
                    acc = __builtin_amdgcn_mfma_f32_16x16x32_bf16(ak, qfrag[ch], acc, 0, 0, 0);
                }
                s[t] = acc;
            }

            // ---- fixed-shift softmax: p = exp(s - d) * (mask ? e^-8 : 0); lane-local ----
            const int qg = qrow + ln;
#pragma unroll
            for (int t = 0; t < 4; ++t) {
                const unsigned nib = (unsigned)(mb >> (t * 16 + quad * 4)) & 0xFu;
#pragma unroll
                for (int r = 0; r < 4; ++r) {
                    const int kg = k0 + t * 16 + quad * 4 + r;
                    int dd = qg - kg; dd = dd < 0 ? -dd : dd;
                    int d2 = LSEQ - dd; dd = d2 < dd ? d2 : dd;
                    float mmv = ((nib >> r) & 1u) ? EXP_NEG8 : 0.f;
                    float p = __expf(s[t][r] - (float)dd) * mmv;
                    l_part += p;
                    s[t][r] = p;
                }
            }

            // ---- O += P V : P-frag is lane-local (keys pre-permuted into V's columns) ----
#pragma unroll
            for (int ch = 0; ch < 2; ++ch) {
                bf16x8 pa;
#pragma unroll
                for (int e = 0; e < 8; ++e)
                    pa[e] = (__bf16)s[ch * 2 + (e >> 2)][e & 3];
#pragma unroll
                for (int nt = 0; nt < 4; ++nt) {
                    const int vr = nt * 16 + ln;
                    const int vc = (ch * 32 + quad * 8) ^ (((vr >> 2) & 7) << 3);
                    bf16x8 bv = *(const bf16x8*)(sVb + vr * 72 + vc);
                    o_acc[nt] = __builtin_amdgcn_mfma_f32_16x16x32_bf16(pa, bv, o_acc[nt], 0, 0, 0);
                }
            }
        }
        // no trailing barrier: next iter writes the other buffer; its barrier orders reuse.
    }

    // ---- epilogue: reduce l over quads, divide, coalesced stores via LDS (two 128-row passes) ----
    float lf = l_part;
    lf += __shfl_xor(lf, 16, 64);
    lf += __shfl_xor(lf, 32, 64);   // lane (ln,*): full denom for q-row qrow+ln
    float inv[4];
#pragma unroll
    for (int r = 0; r < 4; ++r)
        inv[r] = 1.f / __shfl(lf, quad * 4 + r, 16);   // o_acc rows are qrow + quad*4 + r

    float* oscr = (float*)smem_raw;    // [128][68]; stride 68 spreads quad lanes across banks
#pragma unroll
    for (int p = 0; p < 2; ++p) {
        __syncthreads();   // p=0: everyone done reading K/V LDS; p=1: pass-0 stores done
        if (grp == p) {
#pragma unroll
            for (int r = 0; r < 4; ++r)
#pragma unroll
                for (int nt = 0; nt < 4; ++nt)
                    oscr[(w8 * 16 + quad * 4 + r) * 68 + nt * 16 + ln] = o_acc[nt][r] * inv[r];
        }
        __syncthreads();
#pragma unroll
        for (int sidx = 0; sidx < 2; ++sidx) {
            int f   = tid + sidx * 1024;
            int row = f >> 4;
            int c4  = f & 15;
            float4 val = *(const float4*)&oscr[row * 68 + c4 * 4];
            *(float4*)(gO + (size_t)(q0 + p * 128 + row) * RS + c4 * 4) = val;
        }
    }
}

extern "C" void kernel_launch(void* const* d_in, const int* in_sizes, int n_in,
                              void* d_out, int out_size, void* d_ws, size_t ws_size,
                              hipStream_t stream) {
    const float* Q  = (const float*)d_in[0];
    const float* K  = (const float*)d_in[1];
    const float* V  = (const float*)d_in[2];
    const int*   Mk = (const int*)d_in[3];
    float*       O  = (float*)d_out;

    dim3 grid(2 * NH * NBLKQ);   // 256 blocks (1 per CU)
    dim3 block(1024);
    attn_kernel<<<grid, block, 0, stream>>>(Q, K, V, Mk, O);
}

// Round 4
// 99.387 us; speedup vs baseline: 1.0835x; 1.0075x over previous
//
#include <hip/hip_runtime.h>

#define NH 16
#define HD 64
#define LSEQ 2048
#define BQ 256                   // 2 q-tiles merged per block
#define BK 64
#define NBLKQ (LSEQ / BQ)        // 8
#define RS (NH * HD)             // 1024 floats per token row
// k-tiles on a 64-grid offset by -32 from q0: tile j covers keys [256bq - 32 + 64j, +64).
// Group 0 (rows q0..q0+127) needs j=0..2 (window [q0-32,q0+160), margin >= 33);
// group 1 (rows q0+128..q0+255) needs j=2..4. Dropped keys have weight <= e^-23.
#define NTILE 5

typedef __bf16 bf16x8 __attribute__((ext_vector_type(8)));
typedef float f32x4 __attribute__((ext_vector_type(4)));

// exp(-8): folds the fixed softmax shift into the mask multiplier; cancels in O/l.
#define EXP_NEG8 0.00033546262790251185f

__global__ __launch_bounds__(1024, 4)
void attn_kernel(const float* __restrict__ Q,
                 const float* __restrict__ K,
                 const float* __restrict__ V,
                 const int* __restrict__ Mk,
                 float* __restrict__ Out)
{
    // K/V double-buffered: [K0|K1|V0|V1], each 64x72 bf16 (9216 B) = 36864 B.
    // No sP buffer (swapped QK^T keeps P lane-local). Reused after the loop as
    // float oscr[128][68] (34816 B) for the coalesced epilogue (two 128-row passes).
    __shared__ alignas(16) char smem_raw[4 * 64 * 72 * 2];
    __bf16* kvb = (__bf16*)smem_raw;

    const int tid  = threadIdx.x;
    const int wave = tid >> 6;       // 0..15
    const int lane = tid & 63;
    const int ln   = lane & 15;
    const int quad = lane >> 4;
    const int grp  = wave >> 3;      // 0: q-rows [q0,q0+128), active j=0..2; 1: [q0+128,q0+256), j=2..4
    const int w8   = wave & 7;

    const int bq = blockIdx.x & (NBLKQ - 1);
    const int bh = blockIdx.x >> 3;
    const int b  = bh >> 4;
    const int h  = bh & 15;

    const int q0   = bq * BQ;
    const int qrow = q0 + grp * 128 + w8 * 16;

    const size_t bh_off = ((size_t)b * LSEQ) * RS + (size_t)h * HD;
    const float* gQ = Q + bh_off;
    const float* gK = K + bh_off;
    const float* gV = V + bh_off;
    const int*   gM = Mk + (size_t)b * LSEQ;
    float*       gO = Out + bh_off;

    // staging map: tid -> (row 0..63, 16B chunk 0..15); exactly one float4 of K and V per thread
    const int srow = tid >> 4;
    const int sc4  = tid & 15;

    // V key-permutation: PV A-frag slot s (= ch*32 + quad*8 + e) carries actual key
    // pi(s) = (ch*2 + (e>>2))*16 + quad*4 + (e&3). Stage V[k] at column pi^-1(k).
    const int vslot = (srow & 32) | ((srow & 12) << 1) | ((srow & 16) >> 2) | (srow & 3);

    int k0s[NTILE];
#pragma unroll
    for (int j = 0; j < NTILE; ++j) k0s[j] = (q0 - 32 + 64 * j) & (LSEQ - 1);

    // ---- prologue loads: K/V/mask first (feed LDS after barrier), then Q (feeds VALU) ----
    const int r0 = (k0s[0] + srow) & (LSEQ - 1);
    float4 kreg = *(const float4*)(gK + (size_t)r0 * RS + sc4 * 4);
    float4 vreg = *(const float4*)(gV + (size_t)r0 * RS + sc4 * 4);
    // mask as a wave-wide bitset: one load + ballot per wave per tile
    unsigned long long mbits = __ballot(gM[(k0s[0] + lane) & (LSEQ - 1)] != 0);

    // ---- Q fragments (B-operand), pre-scaled by 1/sqrt(D)
    bf16x8 qfrag[2];
#pragma unroll
    for (int c = 0; c < 2; ++c) {
        const float* src = gQ + (size_t)(qrow + ln) * RS + c * 32 + quad * 8;
        float4 f0 = *(const float4*)(src);
        float4 f1 = *(const float4*)(src + 4);
        bf16x8 t;
        t[0] = (__bf16)(f0.x * 0.125f); t[1] = (__bf16)(f0.y * 0.125f);
        t[2] = (__bf16)(f0.z * 0.125f); t[3] = (__bf16)(f0.w * 0.125f);
        t[4] = (__bf16)(f1.x * 0.125f); t[5] = (__bf16)(f1.y * 0.125f);
        t[6] = (__bf16)(f1.z * 0.125f); t[7] = (__bf16)(f1.w * 0.125f);
        qfrag[c] = t;
    }

    f32x4 o_acc[4];
#pragma unroll
    for (int i = 0; i < 4; ++i) o_acc[i] = f32x4{0.f, 0.f, 0.f, 0.f};
    float l_part = 0.f;   // per-lane: softmax denom for q-row (qrow + ln)

#pragma unroll
    for (int j = 0; j < NTILE; ++j) {
        const int bb = j & 1;
        __bf16* sKb = kvb + bb * 4608;          // [64][72]
        __bf16* sVb = kvb + 9216 + bb * 4608;   // [64][72]: [d][pi^-1(k) ^ kappa(d)]

        // ---- store prefetched tile into this iter's buffer ----
        {
            float4 f = kreg;
            __bf16* dst = sKb + srow * 72 + sc4 * 4;
            dst[0] = (__bf16)f.x; dst[1] = (__bf16)f.y;
            dst[2] = (__bf16)f.z; dst[3] = (__bf16)f.w;
            float4 g = vreg;
            // kappa(d) = ((d>>2)&7)<<3; d = sc4*4+c so d>>2 == sc4 for all 4 c's.
            const int vk = vslot ^ ((sc4 & 7) << 3);
            sVb[(sc4 * 4 + 0) * 72 + vk] = (__bf16)g.x;
            sVb[(sc4 * 4 + 1) * 72 + vk] = (__bf16)g.y;
            sVb[(sc4 * 4 + 2) * 72 + vk] = (__bf16)g.z;
            sVb[(sc4 * 4 + 3) * 72 + vk] = (__bf16)g.w;
        }
        const unsigned long long mb = mbits;

        // ---- prefetch next tile ----
        if (j + 1 < NTILE) {
            const int k0n = k0s[j + 1];
            const int rn  = (k0n + srow) & (LSEQ - 1);
            kreg = *(const float4*)(gK + (size_t)rn * RS + sc4 * 4);
            vreg = *(const float4*)(gV + (size_t)rn * RS + sc4 * 4);
            mbits = __ballot(gM[(k0n + lane) & (LSEQ - 1)] != 0);
        }
        __syncthreads();   // single barrier per tile (double-buffered K/V)

        // group-activity: wave-uniform, compile-time j
        const bool act = grp ? (j >= 2) : (j <= 2);
        if (act) {
            // ---- S^T = K Q^T : lane (ln,quad) gets S[key slot t*16+quad*4+r][q = qrow+ln] ----
            const int k0 = k0s[j];
            f32x4 s[4];
#pragma unroll
            for (int t = 0; t < 4; ++t) {
                f32x4 acc = f32x4{0.f, 0.f, 0.f, 0.f};
#pragma unroll
                for (int ch = 0; ch < 2; ++ch) {
                    bf16x8 ak = *(const bf16x8*)(sKb + (t * 16 + ln) * 72 + ch * 32 + quad * 8);
                    acc = __builtin_amdgcn_mfma_f32_16x16x32_bf16(ak, qfrag[ch], acc, 0, 0, 0);
                }
                s[t] = acc;
            }

            // ---- fixed-shift softmax: p = exp(s - d) * (mask ? e^-8 : 0); lane-local ----
            const int qg = qrow + ln;
#pragma unroll
            for (int t = 0; t < 4; ++t) {
                const unsigned nib = (unsigned)(mb >> (t * 16 + quad * 4)) & 0xFu;
#pragma unroll
                for (int r = 0; r < 4; ++r) {
                    const int kg = (k0 + t * 16 + quad * 4 + r) & (LSEQ - 1);
                    int dd = qg - kg; dd = dd < 0 ? -dd : dd;
                    int d2 = LSEQ - dd; dd = d2 < dd ? d2 : dd;
                    float mmv = ((nib >> r) & 1u) ? EXP_NEG8 : 0.f;
                    float p = __expf(s[t][r] - (float)dd) * mmv;
                    l_part += p;
                    s[t][r] = p;
                }
            }

            // ---- O += P V : P-frag is lane-local (keys pre-permuted into V's columns) ----
#pragma unroll
            for (int ch = 0; ch < 2; ++ch) {
                bf16x8 pa;
#pragma unroll
                for (int e = 0; e < 8; ++e)
                    pa[e] = (__bf16)s[ch * 2 + (e >> 2)][e & 3];
#pragma unroll
                for (int nt = 0; nt < 4; ++nt) {
                    const int vr = nt * 16 + ln;
                    const int vc = (ch * 32 + quad * 8) ^ (((vr >> 2) & 7) << 3);
                    bf16x8 bv = *(const bf16x8*)(sVb + vr * 72 + vc);
                    o_acc[nt] = __builtin_amdgcn_mfma_f32_16x16x32_bf16(pa, bv, o_acc[nt], 0, 0, 0);
                }
            }
        }
        // no trailing barrier: next iter writes the other buffer; its barrier orders reuse.
    }

    // ---- epilogue: reduce l over quads, divide, coalesced stores via LDS (two 128-row passes) ----
    float lf = l_part;
    lf += __shfl_xor(lf, 16, 64);
    lf += __shfl_xor(lf, 32, 64);   // lane (ln,*): full denom for q-row qrow+ln
    float inv[4];
#pragma unroll
    for (int r = 0; r < 4; ++r)
        inv[r] = 1.f / __shfl(lf, quad * 4 + r, 16);   // o_acc rows are qrow + quad*4 + r

    float* oscr = (float*)smem_raw;    // [128][68]; stride 68 spreads quad lanes across banks
#pragma unroll
    for (int p = 0; p < 2; ++p) {
        __syncthreads();   // p=0: everyone done reading K/V LDS; p=1: pass-0 stores done
        if (grp == p) {
#pragma unroll
            for (int r = 0; r < 4; ++r)
#pragma unroll
                for (int nt = 0; nt < 4; ++nt)
                    oscr[(w8 * 16 + quad * 4 + r) * 68 + nt * 16 + ln] = o_acc[nt][r] * inv[r];
        }
        __syncthreads();
#pragma unroll
        for (int sidx = 0; sidx < 2; ++sidx) {
            int f   = tid + sidx * 1024;
            int row = f >> 4;
            int c4  = f & 15;
            float4 val = *(const float4*)&oscr[row * 68 + c4 * 4];
            *(float4*)(gO + (size_t)(q0 + p * 128 + row) * RS + c4 * 4) = val;
        }
    }
}

extern "C" void kernel_launch(void* const* d_in, const int* in_sizes, int n_in,
                              void* d_out, int out_size, void* d_ws, size_t ws_size,
                              hipStream_t stream) {
    const float* Q  = (const float*)d_in[0];
    const float* K  = (const float*)d_in[1];
    const float* V  = (const float*)d_in[2];
    const int*   Mk = (const int*)d_in[3];
    float*       O  = (float*)d_out;

    dim3 grid(2 * NH * NBLKQ);   // 256 blocks (1 per CU)
    dim3 block(1024);
    attn_kernel<<<grid, block, 0, stream>>>(Q, K, V, Mk, O);
}

// Round 5
// 98.046 us; speedup vs baseline: 1.0983x; 1.0137x over previous
//
#include <hip/hip_runtime.h>

#define NH 16
#define HD 64
#define LSEQ 2048
#define BQ 256                   // 2 q-tiles merged per block
#define BK 64
#define NBLKQ (LSEQ / BQ)        // 8
#define RS (NH * HD)             // 1024 floats per token row
// k-tiles on a 64-grid offset by -32 from q0: tile j covers keys [256bq - 32 + 64j, +64).
// Group 0 (rows q0..q0+127) needs j=0..2 (min margin 32); group 1 needs j=2..4.
// Dropped keys have weight <= e^-23 relative to the softmax denom.
#define NTILE 5

typedef __bf16 bf16x8 __attribute__((ext_vector_type(8)));
typedef float f32x4 __attribute__((ext_vector_type(4)));

// exp(-8): folds the fixed softmax shift into the mask multiplier; cancels in O/l.
#define EXP_NEG8 0.00033546262790251185f

__global__ __launch_bounds__(1024, 4)
void attn_kernel(const float* __restrict__ Q,
                 const float* __restrict__ K,
                 const float* __restrict__ V,
                 const int* __restrict__ Mk,
                 float* __restrict__ Out)
{
    // K/V double-buffered: [K0|K1|V0|V1], each 64x72 bf16 (9216 B) = 36864 B total.
    // No sP buffer (swapped QK^T keeps P lane-local); no oscr epilogue buffer
    // (direct per-lane dword stores: each quad writes a 64B run, L2 write-combines).
    __shared__ alignas(16) char smem_raw[4 * 64 * 72 * 2];
    __bf16* kvb = (__bf16*)smem_raw;

    const int tid  = threadIdx.x;
    const int wave = tid >> 6;       // 0..15
    const int lane = tid & 63;
    const int ln   = lane & 15;
    const int quad = lane >> 4;
    const int grp  = wave >> 3;      // 0: q-rows [q0,q0+128), active j=0..2; 1: [q0+128,q0+256), j=2..4
    const int w8   = wave & 7;

    const int bq = blockIdx.x & (NBLKQ - 1);
    const int bh = blockIdx.x >> 3;
    const int b  = bh >> 4;
    const int h  = bh & 15;

    const int q0   = bq * BQ;
    const int qrow = q0 + grp * 128 + w8 * 16;

    const size_t bh_off = ((size_t)b * LSEQ) * RS + (size_t)h * HD;
    const float* gQ = Q + bh_off;
    const float* gK = K + bh_off;
    const float* gV = V + bh_off;
    const int*   gM = Mk + (size_t)b * LSEQ;
    float*       gO = Out + bh_off;

    // staging map: tid -> (row 0..63, 16B chunk 0..15); exactly one float4 of K and V per thread
    const int srow = tid >> 4;
    const int sc4  = tid & 15;

    // V key-permutation: PV A-frag slot s (= ch*32 + quad*8 + e) carries actual key
    // pi(s) = (ch*2 + (e>>2))*16 + quad*4 + (e&3). Stage V[k] at column pi^-1(k).
    const int vslot = (srow & 32) | ((srow & 12) << 1) | ((srow & 16) >> 2) | (srow & 3);
    // kappa(d) = ((d>>2)&7)<<3; d = sc4*4+c so d>>2 == sc4 for all 4 c's -> per-thread constant.
    const int vk = vslot ^ ((sc4 & 7) << 3);

    int k0s[NTILE];
#pragma unroll
    for (int j = 0; j < NTILE; ++j) k0s[j] = (q0 - 32 + 64 * j) & (LSEQ - 1);

    // ---- prologue loads: K/V/mask first (feed LDS before first barrier), then Q ----
    const int r0 = (k0s[0] + srow) & (LSEQ - 1);
    float4 kreg = *(const float4*)(gK + (size_t)r0 * RS + sc4 * 4);
    float4 vreg = *(const float4*)(gV + (size_t)r0 * RS + sc4 * 4);
    // mask as a wave-wide bitset: one load + ballot per wave per tile
    unsigned long long mbits = __ballot(gM[(k0s[0] + lane) & (LSEQ - 1)] != 0);

    // ---- Q fragments (B-operand), pre-scaled by 1/sqrt(D)
    bf16x8 qfrag[2];
#pragma unroll
    for (int c = 0; c < 2; ++c) {
        const float* src = gQ + (size_t)(qrow + ln) * RS + c * 32 + quad * 8;
        float4 f0 = *(const float4*)(src);
        float4 f1 = *(const float4*)(src + 4);
        bf16x8 t;
        t[0] = (__bf16)(f0.x * 0.125f); t[1] = (__bf16)(f0.y * 0.125f);
        t[2] = (__bf16)(f0.z * 0.125f); t[3] = (__bf16)(f0.w * 0.125f);
        t[4] = (__bf16)(f1.x * 0.125f); t[5] = (__bf16)(f1.y * 0.125f);
        t[6] = (__bf16)(f1.z * 0.125f); t[7] = (__bf16)(f1.w * 0.125f);
        qfrag[c] = t;
    }

    f32x4 o_acc[4];
#pragma unroll
    for (int i = 0; i < 4; ++i) o_acc[i] = f32x4{0.f, 0.f, 0.f, 0.f};
    float l_part = 0.f;   // per-lane: softmax denom for q-row (qrow + ln)

#pragma unroll
    for (int j = 0; j < NTILE; ++j) {
        const int bb = j & 1;
        __bf16* sKb = kvb + bb * 4608;          // [64][72]
        __bf16* sVb = kvb + 9216 + bb * 4608;   // [64][72]: [d][pi^-1(k) ^ kappa(d)]

        // ---- store prefetched tile into this iter's buffer ----
        {
            float4 f = kreg;
            __bf16* dst = sKb + srow * 72 + sc4 * 4;
            dst[0] = (__bf16)f.x; dst[1] = (__bf16)f.y;
            dst[2] = (__bf16)f.z; dst[3] = (__bf16)f.w;
            float4 g = vreg;
            sVb[(sc4 * 4 + 0) * 72 + vk] = (__bf16)g.x;
            sVb[(sc4 * 4 + 1) * 72 + vk] = (__bf16)g.y;
            sVb[(sc4 * 4 + 2) * 72 + vk] = (__bf16)g.z;
            sVb[(sc4 * 4 + 3) * 72 + vk] = (__bf16)g.w;
        }
        const unsigned long long mb = mbits;

        // ---- prefetch next tile ----
        if (j + 1 < NTILE) {
            const int k0n = k0s[j + 1];
            const int rn  = (k0n + srow) & (LSEQ - 1);
            kreg = *(const float4*)(gK + (size_t)rn * RS + sc4 * 4);
            vreg = *(const float4*)(gV + (size_t)rn * RS + sc4 * 4);
            mbits = __ballot(gM[(k0n + lane) & (LSEQ - 1)] != 0);
        }
        __syncthreads();   // single barrier per tile (double-buffered K/V)

        // group-activity: wave-uniform, compile-time j
        const bool act = grp ? (j >= 2) : (j <= 2);
        if (act) {
            // ---- S^T = K Q^T : lane (ln,quad) gets S[key slot t*16+quad*4+r][q = qrow+ln] ----
            const int k0 = k0s[j];
            f32x4 s[4];
#pragma unroll
            for (int t = 0; t < 4; ++t) {
                f32x4 acc = f32x4{0.f, 0.f, 0.f, 0.f};
#pragma unroll
                for (int ch = 0; ch < 2; ++ch) {
                    bf16x8 ak = *(const bf16x8*)(sKb + (t * 16 + ln) * 72 + ch * 32 + quad * 8);
                    acc = __builtin_amdgcn_mfma_f32_16x16x32_bf16(ak, qfrag[ch], acc, 0, 0, 0);
                }
                s[t] = acc;
            }

            // ---- fixed-shift softmax: p = exp(s - d) * (mask ? e^-8 : 0); lane-local ----
            const int qg = qrow + ln;
#pragma unroll
            for (int t = 0; t < 4; ++t) {
                const unsigned nib = (unsigned)(mb >> (t * 16 + quad * 4)) & 0xFu;
#pragma unroll
                for (int r = 0; r < 4; ++r) {
                    const int kg = (k0 + t * 16 + quad * 4 + r) & (LSEQ - 1);
                    int dd = qg - kg; dd = dd < 0 ? -dd : dd;
                    int d2 = LSEQ - dd; dd = d2 < dd ? d2 : dd;
                    float mmv = ((nib >> r) & 1u) ? EXP_NEG8 : 0.f;
                    float p = __expf(s[t][r] - (float)dd) * mmv;
                    l_part += p;
                    s[t][r] = p;
                }
            }

            // ---- O += P V : P-frag is lane-local (keys pre-permuted into V's columns) ----
#pragma unroll
            for (int ch = 0; ch < 2; ++ch) {
                bf16x8 pa;
#pragma unroll
                for (int e = 0; e < 8; ++e)
                    pa[e] = (__bf16)s[ch * 2 + (e >> 2)][e & 3];
#pragma unroll
                for (int nt = 0; nt < 4; ++nt) {
                    const int vr = nt * 16 + ln;
                    const int vc = (ch * 32 + quad * 8) ^ (((vr >> 2) & 7) << 3);
                    bf16x8 bv = *(const bf16x8*)(sVb + vr * 72 + vc);
                    o_acc[nt] = __builtin_amdgcn_mfma_f32_16x16x32_bf16(pa, bv, o_acc[nt], 0, 0, 0);
                }
            }
        }

        // ---- group 0 epilogue in C_3's shadow: done computing at j=2; normalize + store its
        // 128 rows while group 1 computes tile 3 and tile 4's loads stream. No barrier needed:
        // stores touch only rows [q0, q0+128), disjoint from everything else.
        if (j == 3 && grp == 0) {
            float lf = l_part;
            lf += __shfl_xor(lf, 16, 64);
            lf += __shfl_xor(lf, 32, 64);   // lane (ln,*): full denom for q-row qrow+ln
            float inv[4];
#pragma unroll
            for (int r = 0; r < 4; ++r)
                inv[r] = 1.f / __shfl(lf, quad * 4 + r, 16);   // o_acc rows are qrow + quad*4 + r
#pragma unroll
            for (int nt = 0; nt < 4; ++nt)
#pragma unroll
                for (int r = 0; r < 4; ++r)
                    gO[(size_t)(qrow + quad * 4 + r) * RS + nt * 16 + ln] = o_acc[nt][r] * inv[r];
        }
        // no trailing barrier: next iter writes the other buffer; its barrier orders reuse.
    }

    // ---- group 1 epilogue: only remaining tail (32 KB of stores per block) ----
    if (grp == 1) {
        float lf = l_part;
        lf += __shfl_xor(lf, 16, 64);
        lf += __shfl_xor(lf, 32, 64);
        float inv[4];
#pragma unroll
        for (int r = 0; r < 4; ++r)
            inv[r] = 1.f / __shfl(lf, quad * 4 + r, 16);
#pragma unroll
        for (int nt = 0; nt < 4; ++nt)
#pragma unroll
            for (int r = 0; r < 4; ++r)
                gO[(size_t)(qrow + quad * 4 + r) * RS + nt * 16 + ln] = o_acc[nt][r] * inv[r];
    }
}

extern "C" void kernel_launch(void* const* d_in, const int* in_sizes, int n_in,
                              void* d_out, int out_size, void* d_ws, size_t ws_size,
                              hipStream_t stream) {
    const float* Q  = (const float*)d_in[0];
    const float* K  = (const float*)d_in[1];
    const float* V  = (const float*)d_in[2];
    const int*   Mk = (const int*)d_in[3];
    float*       O  = (float*)d_out;

    dim3 grid(2 * NH * NBLKQ);   // 256 blocks (1 per CU)
    dim3 block(1024);
    attn_kernel<<<grid, block, 0, stream>>>(Q, K, V, Mk, O);
}